// Round 14
// baseline (949.511 us; speedup 1.0000x reference)
//
#include <hip/hip_runtime.h>
#include <stdint.h>

typedef __attribute__((ext_vector_type(8))) short v8s;
typedef __attribute__((ext_vector_type(4))) float v4f;

#define NBATCH 32
#define SEQ 2048
#define DHEAD 64

__device__ __forceinline__ unsigned short f2bf(float f) {
  unsigned int x = __float_as_uint(f);
  x += 0x7fffu + ((x >> 16) & 1u);
  return (unsigned short)(x >> 16);
}

__device__ __forceinline__ float bf2f(short s) {
  return __uint_as_float(((unsigned int)(unsigned short)s) << 16);
}

// ---- prepass: fp32 -> bf16 copy, Q and K in one launch (blockIdx.y picks) ----
// Q is PRE-SCALED by 0.125*log2(e): exp(S/8) = exp2((Q*0.18033688) . K).
__global__ void cvt_bf16_qk_k(const float* __restrict__ Q, const float* __restrict__ K,
                              unsigned short* __restrict__ Qb,
                              unsigned short* __restrict__ Kb, int n4) {
  int i = blockIdx.x * blockDim.x + threadIdx.x;
  if (i >= n4) return;
  const float* src = blockIdx.y ? K : Q;
  unsigned short* dst = blockIdx.y ? Kb : Qb;
  const float sc = blockIdx.y ? 1.0f : 0.18033688f;
  float4 v = ((const float4*)src)[i];
  ushort4 o;
  o.x = f2bf(v.x * sc); o.y = f2bf(v.y * sc);
  o.z = f2bf(v.z * sc); o.w = f2bf(v.w * sc);
  ((ushort4*)dst)[i] = o;
}

// ---- prepass: V (n,k,d) -> Vt (n,d,k) bf16 ----
__global__ void vtrans_k(const float* __restrict__ V,
                         unsigned short* __restrict__ Vt) {
  __shared__ float tile[64][65];
  int n = blockIdx.y, k0 = blockIdx.x * 64;
  int t = threadIdx.x;
  int c = t & 63, rb = t >> 6;
#pragma unroll
  for (int it = 0; it < 16; ++it) {
    int r = it * 4 + rb;
    tile[r][c] = V[((size_t)(n * SEQ + k0 + r)) * DHEAD + c];
  }
  __syncthreads();
#pragma unroll
  for (int it = 0; it < 16; ++it) {
    int d = it * 4 + rb;
    Vt[((size_t)(n * DHEAD + d)) * SEQ + k0 + c] = f2bf(tile[c][d]);
  }
}

// ---- prepass: attn_mask (m,k) int -> bits along k: amB[m][k/32] ----
__global__ void pack_amB_k(const int* __restrict__ am, unsigned int* __restrict__ amB) {
  int tid = blockIdx.x * blockDim.x + threadIdx.x;  // SEQ*64 = 131072 threads
  int w = tid & 63, m = tid >> 6;
  unsigned int bits = 0;
#pragma unroll 4
  for (int i = 0; i < 32; ++i)
    bits |= (am[(size_t)m * SEQ + w * 32 + i] != 0 ? 1u : 0u) << i;
  amB[m * 64 + w] = bits;
}

// ---- prepass: key_padding_mask (n,k) int -> bits kpmB[n][k/32] ----
__global__ void pack_kpm_k(const int* __restrict__ kpm, unsigned int* __restrict__ kpmB) {
  int tid = blockIdx.x * blockDim.x + threadIdx.x;  // 2048 threads
  if (tid >= NBATCH * 64) return;
  int n = tid >> 6, w = tid & 63;
  unsigned int bits = 0;
#pragma unroll 4
  for (int i = 0; i < 32; ++i)
    bits |= (kpm[n * SEQ + w * 32 + i] != 0 ? 1u : 0u) << i;
  kpmB[n * 64 + w] = bits;
}

// ================= PHASE-SPLIT (R13): three kernels for attribution ========
// qk_k: QK^T + mask + exp -> unnormalized bf16 P (global) + row sums (global)
// expand_k: outW = P * (1/rowsum), pure streaming
// pv_k: O = (P x V) * rinv, P fragments loaded directly from global

// ---- kernel A: P1 + rowsum -> Pg, Wsum ----
__global__ __launch_bounds__(512, 4)
void qk_k(const unsigned short* __restrict__ Qb,
          const unsigned short* __restrict__ Kb,
          const unsigned int* __restrict__ amB,
          const unsigned int* __restrict__ kpmB,
          unsigned short* __restrict__ Pg, float* __restrict__ Wsum) {
  // [0,65536): P bf16, 16 rows x 4096 B, XOR-swizzled
  // [65536,66048): wsum[8][16]
  __shared__ __align__(16) char smem[66048];

  const int b = blockIdx.x;
  const int xcd = b & 7, slot = b >> 3;
  const int n = xcd + ((slot >> 7) << 3);
  const int row0 = (slot & 127) * 16;

  const int tid = threadIdx.x;
  const int wave = tid >> 6, lane = tid & 63;
  const int quad = lane >> 4, lq = lane & 15;
  const int colw = wave * 256;

  const unsigned short* qp = Qb + ((size_t)(n * SEQ + row0 + lq)) * DHEAD + quad * 8;
  v8s a0 = *(const v8s*)qp;
  v8s a1 = *(const v8s*)(qp + 32);

  const unsigned int* amRow = amB + (size_t)(row0 + lq) * 64;
  const unsigned int* kpmRow = kpmB + n * 64 + (colw >> 5);
  unsigned int mwv[8];
#pragma unroll
  for (int w2 = 0; w2 < 8; ++w2)
    mwv[w2] = amRow[(colw >> 5) + w2] | kpmRow[w2];

  // depth-4 ring prefetch of K fragments (R12 code, verified)
  const unsigned short* kbase =
      Kb + ((size_t)(n * SEQ + colw + lq)) * DHEAD + quad * 8;
  v8s kb0[4], kb1[4];
#pragma unroll
  for (int i = 0; i < 4; ++i) {
    const unsigned short* kp = kbase + (size_t)(i * 16) * DHEAD;
    kb0[i] = *(const v8s*)kp;
    kb1[i] = *(const v8s*)(kp + 32);
  }

  float rsum = 0.f;
#pragma unroll
  for (int kt = 0; kt < 16; ++kt) {
    v8s b0 = kb0[kt & 3], b1 = kb1[kt & 3];
    if (kt < 12) {
      const unsigned short* kp = kbase + (size_t)((kt + 4) * 16) * DHEAD;
      kb0[kt & 3] = *(const v8s*)kp;
      kb1[kt & 3] = *(const v8s*)(kp + 32);
    }
    v4f c = {0.f, 0.f, 0.f, 0.f};
    c = __builtin_amdgcn_mfma_f32_16x16x32_bf16(b0, a0, c, 0, 0, 0);  // A=K, B=Q
    c = __builtin_amdgcn_mfma_f32_16x16x32_bf16(b1, a1, c, 0, 0, 0);
    const unsigned int mw = mwv[kt >> 1];
    const int bitbase = (kt & 1) * 16 + quad * 4;
    float e0, e1, e2, e3;
    e0 = (mw >> (bitbase + 0)) & 1u ? 0.f : exp2f(c[0]);
    e1 = (mw >> (bitbase + 1)) & 1u ? 0.f : exp2f(c[1]);
    e2 = (mw >> (bitbase + 2)) & 1u ? 0.f : exp2f(c[2]);
    e3 = (mw >> (bitbase + 3)) & 1u ? 0.f : exp2f(c[3]);
    rsum += (e0 + e1) + (e2 + e3);
    uint2 dd;
    dd.x = ((unsigned int)f2bf(e0)) | (((unsigned int)f2bf(e1)) << 16);
    dd.y = ((unsigned int)f2bf(e2)) | (((unsigned int)f2bf(e3)) << 16);
    const int col0 = colw + kt * 16 + quad * 4;
    *(uint2*)(smem + lq * 4096 +
              ((((col0 >> 3) ^ (lq & 7)) << 4) | ((quad & 1) << 3))) = dd;
  }

  rsum += __shfl_xor(rsum, 16);
  rsum += __shfl_xor(rsum, 32);
  float* wsum = (float*)(smem + 65536);
  if (quad == 0) wsum[wave * 16 + lq] = rsum;
  __syncthreads();

  // store unnormalized bf16 P rows, coalesced (wave w -> rows 2w, 2w+1)
  unsigned short* pbase = Pg + ((size_t)(n * SEQ + row0)) * SEQ;
#pragma unroll
  for (int ps = 0; ps < 8; ++ps) {
    const int row = wave * 2 + (ps & 1);
    const int cb8 = lane + ((ps >> 1) << 6);  // 16B-block index 0..255
    v8s pv = *(const v8s*)(smem + row * 4096 + ((cb8 ^ (row & 7)) << 4));
    *(v8s*)(pbase + (size_t)row * SEQ + (cb8 << 3)) = pv;
  }

  // store row sums
  if (tid < 16) {
    float s = 0.f;
#pragma unroll
    for (int w = 0; w < 8; ++w) s += wsum[w * 16 + tid];
    Wsum[(size_t)n * SEQ + row0 + tid] = s;
  }
}

// ---- kernel B1: outW = P * (1/rowsum), one block per row, pure streaming ----
__global__ void expand_k(const unsigned short* __restrict__ Pg,
                         const float* __restrict__ Wsum,
                         float* __restrict__ outW) {
  const int bid = blockIdx.x;  // 0..65535 = n*SEQ + row
  const float rinv = 1.0f / Wsum[bid];
  v8s pv = *(const v8s*)(Pg + (size_t)bid * SEQ + threadIdx.x * 8);
  float* dst = outW + (size_t)bid * SEQ + threadIdx.x * 8;
  v4f f0, f1;
  f0.x = bf2f(pv[0]) * rinv; f0.y = bf2f(pv[1]) * rinv;
  f0.z = bf2f(pv[2]) * rinv; f0.w = bf2f(pv[3]) * rinv;
  f1.x = bf2f(pv[4]) * rinv; f1.y = bf2f(pv[5]) * rinv;
  f1.z = bf2f(pv[6]) * rinv; f1.w = bf2f(pv[7]) * rinv;
  ((v4f*)dst)[0] = f0;
  ((v4f*)dst)[1] = f1;
}

// ---- kernel B2: O = (P x V) * rinv; P fragments direct from global ----
__global__ __launch_bounds__(512)
void pv_k(const unsigned short* __restrict__ Pg,
          const unsigned short* __restrict__ Vt,
          const float* __restrict__ Wsum, float* __restrict__ outO) {
  __shared__ __align__(16) float olds[8 * 1088];  // [8][16][68] padded, 34816 B

  const int b = blockIdx.x;
  const int xcd = b & 7, slot = b >> 3;
  const int n = xcd + ((slot >> 7) << 3);
  const int row0 = (slot & 127) * 16;

  const int tid = threadIdx.x;
  const int wave = tid >> 6, lane = tid & 63;
  const int quad = lane >> 4, lq = lane & 15;
  const int colw = wave * 256;

  const unsigned short* prow = Pg + ((size_t)(n * SEQ + row0 + lq)) * SEQ;
  const unsigned short* vtbase =
      Vt + ((size_t)(n * DHEAD + lq)) * SEQ + colw + quad * 8;

  v4f acc[4] = {{0.f,0.f,0.f,0.f},{0.f,0.f,0.f,0.f},{0.f,0.f,0.f,0.f},{0.f,0.f,0.f,0.f}};
#pragma unroll
  for (int ch = 0; ch < 8; ++ch) {
    const int cb = colw + ch * 32;
    v8s ap = *(const v8s*)(prow + cb + quad * 8);
#pragma unroll
    for (int dt = 0; dt < 4; ++dt) {
      v8s bp = *(const v8s*)(vtbase + (size_t)(dt * 16) * SEQ + ch * 32);
      acc[dt] = __builtin_amdgcn_mfma_f32_16x16x32_bf16(ap, bp, acc[dt], 0, 0, 0);
    }
  }

  float rinv[4];
#pragma unroll
  for (int r = 0; r < 4; ++r)
    rinv[r] = 1.0f / Wsum[(size_t)n * SEQ + row0 + quad * 4 + r];

#pragma unroll
  for (int dt = 0; dt < 4; ++dt)
#pragma unroll
    for (int r = 0; r < 4; ++r)
      olds[wave * 1088 + (quad * 4 + r) * 68 + dt * 16 + lq] = acc[dt][r] * rinv[r];
  __syncthreads();
#pragma unroll
  for (int s = 0; s < 2; ++s) {
    int e = tid + s * 512;
    int row = e >> 6, d = e & 63;
    float a = 0.f;
#pragma unroll
    for (int w = 0; w < 8; ++w) a += olds[w * 1088 + row * 68 + d];
    outO[((size_t)(n * SEQ + row0 + row)) * DHEAD + d] = a;
  }
}

extern "C" void kernel_launch(void* const* d_in, const int* in_sizes, int n_in,
                              void* d_out, int out_size, void* d_ws, size_t ws_size,
                              hipStream_t stream) {
  const float* Q = (const float*)d_in[0];
  const float* K = (const float*)d_in[1];
  const float* V = (const float*)d_in[2];
  const int* kpm = (const int*)d_in[3];
  const int* am = (const int*)d_in[4];

  float* outO = (float*)d_out;
  float* outW = outO + (size_t)NBATCH * SEQ * DHEAD;

  char* ws = (char*)d_ws;
  unsigned short* Qb = (unsigned short*)ws;                       // 0..8 MiB
  unsigned short* Kb = (unsigned short*)(ws + (8u << 20));        // 8..16 MiB
  unsigned short* Vt = (unsigned short*)(ws + (16u << 20));       // 16..24 MiB
  unsigned int* amB = (unsigned int*)(ws + (24u << 20));          // 512 KiB
  unsigned int* kpmB = (unsigned int*)(ws + (24u << 20) + (1u << 19));  // 8 KiB
  float* Wsum = (float*)(ws + (25u << 20));                       // 256 KiB
  unsigned short* Pg = (unsigned short*)(ws + (32u << 20));       // 256 MiB

  const int n4 = NBATCH * SEQ * DHEAD / 4;
  cvt_bf16_qk_k<<<dim3(n4 / 256, 2), 256, 0, stream>>>(Q, K, Qb, Kb, n4);
  vtrans_k<<<dim3(SEQ / 64, NBATCH), 256, 0, stream>>>(V, Vt);
  pack_amB_k<<<(SEQ * 64) / 256, 256, 0, stream>>>(am, amB);
  pack_kpm_k<<<8, 256, 0, stream>>>(kpm, kpmB);
  qk_k<<<NBATCH * (SEQ / 16), 512, 0, stream>>>(Qb, Kb, amB, kpmB, Pg, Wsum);
  expand_k<<<NBATCH * SEQ, 256, 0, stream>>>(Pg, Wsum, outW);
  pv_k<<<NBATCH * (SEQ / 16), 512, 0, stream>>>(Pg, Vt, Wsum, outO);
}